// Round 2
// baseline (347.668 us; speedup 1.0000x reference)
//
#include <hip/hip_runtime.h>
#include <hip/hip_fp16.h>
#include <stdint.h>

#define LOG2_HASHMAP_SIZE 19
#define HASHMAP_SIZE (1u << LOG2_HASHMAP_SIZE)
#define HASHMAP_MASK (HASHMAP_SIZE - 1u)
#define N_LEVELS 4

// Level 0: res=30 -> 31 vertices per axis. Dense grid fits in LDS as half2.
#define R0 31
#define DENSE0_N (R0 * R0 * R0)        // 29791 vertices
#define DENSE0_BYTES (DENSE0_N * 4)    // half2 per vertex = 119164 B < 160 KiB

// native vector type usable with __builtin_nontemporal_store
typedef float v4f __attribute__((ext_vector_type(4)));

__device__ __forceinline__ uint32_t hash3(uint32_t ix, uint32_t iy, uint32_t iz) {
    return (ix ^ (iy * 11614769u) ^ (iz * 2654435761u)) & HASHMAP_MASK;
}

// Per level: h = ix ^ iy*P1 ^ iz*P2 (masked). XOR-linear in ix, so for even ix
// the x-corner pair {ix, ix+1} lands in the aligned table pair {h&~1, h|1} ->
// one float4 load returns both corners' float2 embeddings.
__device__ __forceinline__ float2 level_embed_p(float px, float py, float pz,
                                                const float* __restrict__ tables,
                                                int li, float r)
{
    const uint32_t P1 = 11614769u;
    const uint32_t P2 = 2654435761u;

    const float sx = px * r, sy = py * r, sz = pz * r;
    const float bx = floorf(sx), by = floorf(sy), bz = floorf(sz);
    const float tx = sx - bx, ty = sy - by, tz = sz - bz;
    const float ux = 1.0f - tx, uy = 1.0f - ty, uz = 1.0f - tz;

    const uint32_t ix = (uint32_t)(int)bx;
    const uint32_t iy = (uint32_t)(int)by;
    const uint32_t iz = (uint32_t)(int)bz;

    const uint32_t hy0 = iy * P1, hy1 = (iy + 1u) * P1;
    const uint32_t hz0 = iz * P2, hz1 = (iz + 1u) * P2;

    uint32_t S[4];
    float W[4];
    S[0] = hy0 ^ hz0;  W[0] = uy * uz;
    S[1] = hy0 ^ hz1;  W[1] = uy * tz;
    S[2] = hy1 ^ hz0;  W[2] = ty * uz;
    S[3] = hy1 ^ hz1;  W[3] = ty * tz;

    const float* tab = tables + (size_t)li * HASHMAP_SIZE * 2;
    const float2* __restrict__ tab2 = (const float2*)tab;
    const float4* __restrict__ tab4 = (const float4*)tab;

    float f0 = 0.0f, f1 = 0.0f;

    if ((ix & 1u) == 0u) {
        // even ix: one aligned float4 per (y,z) combo covers both x-corners
        #pragma unroll
        for (int c = 0; c < 4; ++c) {
            const uint32_t h0 = (ix ^ S[c]) & HASHMAP_MASK;
            const float4 v = tab4[h0 >> 1];
            const bool hi = (h0 & 1u);
            const float e0x = hi ? v.z : v.x;
            const float e0y = hi ? v.w : v.y;
            const float e1x = hi ? v.x : v.z;
            const float e1y = hi ? v.y : v.w;
            f0 += W[c] * (ux * e0x + tx * e1x);
            f1 += W[c] * (ux * e0y + tx * e1y);
        }
    } else {
        // odd ix: {ix, ix+1} straddles aligned pairs; two float2 gathers
        #pragma unroll
        for (int c = 0; c < 4; ++c) {
            const uint32_t h0 = (ix ^ S[c]) & HASHMAP_MASK;
            const uint32_t h1 = ((ix + 1u) ^ S[c]) & HASHMAP_MASK;
            const float2 e0 = tab2[h0];
            const float2 e1 = tab2[h1];
            f0 += W[c] * (ux * e0.x + tx * e1.x);
            f1 += W[c] * (ux * e0.y + tx * e1.y);
        }
    }
    return make_float2(f0, f1);
}

// Setup: materialize the level-0 dense vertex grid (hash applied once per
// vertex instead of once per point) packed as half2. |v| <= 1e-4 so fp16
// rounding error <= ~5e-8 absolute; interpolation weights are convex.
__global__ __launch_bounds__(256) void build_dense0(
    const float* __restrict__ tables, uint32_t* __restrict__ dense0)
{
    const int v = blockIdx.x * blockDim.x + threadIdx.x;
    if (v >= DENSE0_N) return;
    const int vx = v / (R0 * R0);
    const int rem = v - vx * (R0 * R0);
    const int vy = rem / R0;
    const int vz = rem - vy * R0;
    const uint32_t h = hash3((uint32_t)vx, (uint32_t)vy, (uint32_t)vz);
    const float2 e = ((const float2*)tables)[h];   // level-0 table is at offset 0
    const __half2 p = __floats2half2_rn(e.x, e.y);
    dense0[v] = *(const uint32_t*)&p;
}

extern __shared__ uint32_t s_dense[];   // DENSE0_N packed half2

// Fused: all 4 levels in one pass. Level 0 gathers come from LDS (off the
// global scattered-request pipe); levels 1..3 keep the pair-gather path.
__global__ __launch_bounds__(1024) void fused_kernel(
    const float* __restrict__ x, const float* __restrict__ tables,
    const uint32_t* __restrict__ dense0, float* __restrict__ out, int n)
{
    // cooperative stage of the 119 KB dense level-0 grid
    for (int i = threadIdx.x; i < DENSE0_N; i += 1024)
        s_dense[i] = dense0[i];
    __syncthreads();

    const size_t stride = (size_t)gridDim.x * 1024;
    for (size_t i = (size_t)blockIdx.x * 1024 + threadIdx.x; i < (size_t)n; i += stride) {
        const float px = __builtin_nontemporal_load(x + 3 * i + 0);
        const float py = __builtin_nontemporal_load(x + 3 * i + 1);
        const float pz = __builtin_nontemporal_load(x + 3 * i + 2);

        // levels 1..3: global hash-table gathers (long latency; issue first)
        const float2 e1 = level_embed_p(px, py, pz, tables, 1, 80.0f);
        const float2 e2 = level_embed_p(px, py, pz, tables, 2, 210.0f);
        const float2 e3 = level_embed_p(px, py, pz, tables, 3, 512.0f);

        // level 0 from LDS dense grid
        const float sx = px * 30.0f, sy = py * 30.0f, sz = pz * 30.0f;
        const float bx = floorf(sx), by = floorf(sy), bz = floorf(sz);
        const float tx = sx - bx, ty = sy - by, tz = sz - bz;
        const float uxv = 1.0f - tx, uyv = 1.0f - ty, uzv = 1.0f - tz;
        const int ix = (int)bx, iy = (int)by, iz = (int)bz;
        const int lin = (ix * R0 + iy) * R0 + iz;

        float f0 = 0.0f, f1 = 0.0f;
        #pragma unroll
        for (int dx = 0; dx < 2; ++dx) {
            const float wx = dx ? tx : uxv;
            #pragma unroll
            for (int dy = 0; dy < 2; ++dy) {
                const float wxy = wx * (dy ? ty : uyv);
                const int base = lin + (dx * R0 + dy) * R0;   // z-corners adjacent
                const uint32_t p0 = s_dense[base];
                const uint32_t p1 = s_dense[base + 1];
                const float2 c0 = __half22float2(*(const __half2*)&p0);
                const float2 c1 = __half22float2(*(const __half2*)&p1);
                f0 += wxy * (uzv * c0.x + tz * c1.x);
                f1 += wxy * (uzv * c0.y + tz * c1.y);
            }
        }

        v4f* op = (v4f*)(out + 8 * i);
        v4f lo = {f0, f1, e1.x, e1.y};
        v4f hi = {e2.x, e2.y, e3.x, e3.y};
        __builtin_nontemporal_store(lo, op);
        __builtin_nontemporal_store(hi, op + 1);
    }
}

// Fallback (ws too small / attribute failure): per-level pass into out.
__global__ __launch_bounds__(256) void pass_direct_kernel(
    const float* __restrict__ x, const float* __restrict__ tables,
    float* __restrict__ out, int li, float r, int n)
{
    const int i = blockIdx.x * blockDim.x + threadIdx.x;
    if (i >= n) return;
    const float px = x[3 * (size_t)i + 0];
    const float py = x[3 * (size_t)i + 1];
    const float pz = x[3 * (size_t)i + 2];
    const float2 e = level_embed_p(px, py, pz, tables, li, r);
    float2* op = (float2*)(out + 8 * (size_t)i + 2 * li);
    *op = e;
}

extern "C" void kernel_launch(void* const* d_in, const int* in_sizes, int n_in,
                              void* d_out, int out_size, void* d_ws, size_t ws_size,
                              hipStream_t stream) {
    const float* x = (const float*)d_in[0];        // [N, 3]
    const float* tables = (const float*)d_in[1];   // [4, 2^19, 2]
    float* out = (float*)d_out;                    // [N, 8]
    const int n = in_sizes[0] / 3;

    bool fused_ok = (ws_size >= (size_t)DENSE0_BYTES);
    if (fused_ok) {
        static int attr_ok = -1;
        if (attr_ok < 0) {
            attr_ok = (hipFuncSetAttribute(
                           reinterpret_cast<const void*>(fused_kernel),
                           hipFuncAttributeMaxDynamicSharedMemorySize,
                           DENSE0_BYTES) == hipSuccess) ? 1 : 0;
        }
        fused_ok = (attr_ok == 1);
    }

    if (fused_ok) {
        uint32_t* dense0 = (uint32_t*)d_ws;
        build_dense0<<<(DENSE0_N + 255) / 256, 256, 0, stream>>>(tables, dense0);
        // 119 KB LDS -> 1 block/CU (16 waves). 512 blocks = two scheduling
        // rounds across 256 CUs for load balance; grid-stride keeps lanes
        // on consecutive points (coalesced x/out).
        fused_kernel<<<512, 1024, DENSE0_BYTES, stream>>>(x, tables, dense0, out, n);
    } else {
        const float res[N_LEVELS] = {30.0f, 80.0f, 210.0f, 512.0f};
        const int block = 256;
        const int grid = (n + block - 1) / block;
        for (int li = 0; li < N_LEVELS; ++li) {
            pass_direct_kernel<<<grid, block, 0, stream>>>(
                x, tables, out, li, res[li], n);
        }
    }
}

// Round 3
// 248.988 us; speedup vs baseline: 1.3963x; 1.3963x over previous
//
#include <hip/hip_runtime.h>
#include <hip/hip_fp16.h>
#include <stdint.h>

#define LOG2_HASHMAP_SIZE 19
#define HASHMAP_SIZE (1u << LOG2_HASHMAP_SIZE)
#define HASHMAP_MASK (HASHMAP_SIZE - 1u)
#define N_LEVELS 4

// Level 0: res=30 -> 31 vertices per axis. Dense grid fits in LDS as half2.
#define R0 31
#define DENSE0_N (R0 * R0 * R0)        // 29791 vertices
#define DENSE0_BYTES (DENSE0_N * 4)    // half2 per vertex = 119164 B < 160 KiB

// native vector types usable with __builtin_nontemporal_*
typedef float v4f __attribute__((ext_vector_type(4)));
typedef float v2f __attribute__((ext_vector_type(2)));

__device__ __forceinline__ uint32_t hash3(uint32_t ix, uint32_t iy, uint32_t iz) {
    return (ix ^ (iy * 11614769u) ^ (iz * 2654435761u)) & HASHMAP_MASK;
}

// ---------------- fp32 path (fallback only) ----------------
__device__ __forceinline__ float2 level_embed_p(float px, float py, float pz,
                                                const float* __restrict__ tables,
                                                int li, float r)
{
    const uint32_t P1 = 11614769u;
    const uint32_t P2 = 2654435761u;

    const float sx = px * r, sy = py * r, sz = pz * r;
    const float bx = floorf(sx), by = floorf(sy), bz = floorf(sz);
    const float tx = sx - bx, ty = sy - by, tz = sz - bz;
    const float ux = 1.0f - tx, uy = 1.0f - ty, uz = 1.0f - tz;

    const uint32_t ix = (uint32_t)(int)bx;
    const uint32_t iy = (uint32_t)(int)by;
    const uint32_t iz = (uint32_t)(int)bz;

    const uint32_t hy0 = iy * P1, hy1 = (iy + 1u) * P1;
    const uint32_t hz0 = iz * P2, hz1 = (iz + 1u) * P2;

    uint32_t S[4];
    float W[4];
    S[0] = hy0 ^ hz0;  W[0] = uy * uz;
    S[1] = hy0 ^ hz1;  W[1] = uy * tz;
    S[2] = hy1 ^ hz0;  W[2] = ty * uz;
    S[3] = hy1 ^ hz1;  W[3] = ty * tz;

    const float* tab = tables + (size_t)li * HASHMAP_SIZE * 2;
    const float2* __restrict__ tab2 = (const float2*)tab;
    const float4* __restrict__ tab4 = (const float4*)tab;

    float f0 = 0.0f, f1 = 0.0f;
    if ((ix & 1u) == 0u) {
        #pragma unroll
        for (int c = 0; c < 4; ++c) {
            const uint32_t h0 = (ix ^ S[c]) & HASHMAP_MASK;
            const float4 v = tab4[h0 >> 1];
            const bool hi = (h0 & 1u);
            const float e0x = hi ? v.z : v.x;
            const float e0y = hi ? v.w : v.y;
            const float e1x = hi ? v.x : v.z;
            const float e1y = hi ? v.y : v.w;
            f0 += W[c] * (ux * e0x + tx * e1x);
            f1 += W[c] * (ux * e0y + tx * e1y);
        }
    } else {
        #pragma unroll
        for (int c = 0; c < 4; ++c) {
            const uint32_t h0 = (ix ^ S[c]) & HASHMAP_MASK;
            const uint32_t h1 = ((ix + 1u) ^ S[c]) & HASHMAP_MASK;
            const float2 e0 = tab2[h0];
            const float2 e1 = tab2[h1];
            f0 += W[c] * (ux * e0.x + tx * e1.x);
            f1 += W[c] * (ux * e0.y + tx * e1.y);
        }
    }
    return make_float2(f0, f1);
}

// ---------------- fp16-table gather path ----------------
// t16: one level's table packed as half2 per entry (4B). Same even/odd pair
// trick: even ix -> one aligned 8B load covers both x-corners.
__device__ __forceinline__ float2 level_embed_h16(float px, float py, float pz,
                                                  const uint32_t* __restrict__ t16,
                                                  float r)
{
    const uint32_t P1 = 11614769u;
    const uint32_t P2 = 2654435761u;

    const float sx = px * r, sy = py * r, sz = pz * r;
    const float bx = floorf(sx), by = floorf(sy), bz = floorf(sz);
    const float tx = sx - bx, ty = sy - by, tz = sz - bz;
    const float ux = 1.0f - tx, uy = 1.0f - ty, uz = 1.0f - tz;

    const uint32_t ix = (uint32_t)(int)bx;
    const uint32_t iy = (uint32_t)(int)by;
    const uint32_t iz = (uint32_t)(int)bz;

    const uint32_t hy0 = iy * P1, hy1 = (iy + 1u) * P1;
    const uint32_t hz0 = iz * P2, hz1 = (iz + 1u) * P2;

    uint32_t S[4];
    float W[4];
    S[0] = hy0 ^ hz0;  W[0] = uy * uz;
    S[1] = hy0 ^ hz1;  W[1] = uy * tz;
    S[2] = hy1 ^ hz0;  W[2] = ty * uz;
    S[3] = hy1 ^ hz1;  W[3] = ty * tz;

    float f0 = 0.0f, f1 = 0.0f;
    if ((ix & 1u) == 0u) {
        #pragma unroll
        for (int c = 0; c < 4; ++c) {
            const uint32_t h0 = (ix ^ S[c]) & HASHMAP_MASK;
            const uint2 v = ((const uint2*)t16)[h0 >> 1];   // entries {h0&~1, h0|1}
            const uint32_t p0 = (h0 & 1u) ? v.y : v.x;      // corner ix
            const uint32_t p1 = (h0 & 1u) ? v.x : v.y;      // corner ix+1
            const float2 e0 = __half22float2(*(const __half2*)&p0);
            const float2 e1 = __half22float2(*(const __half2*)&p1);
            f0 += W[c] * (ux * e0.x + tx * e1.x);
            f1 += W[c] * (ux * e0.y + tx * e1.y);
        }
    } else {
        #pragma unroll
        for (int c = 0; c < 4; ++c) {
            const uint32_t h0 = (ix ^ S[c]) & HASHMAP_MASK;
            const uint32_t h1 = ((ix + 1u) ^ S[c]) & HASHMAP_MASK;
            const uint32_t p0 = t16[h0];
            const uint32_t p1 = t16[h1];
            const float2 e0 = __half22float2(*(const __half2*)&p0);
            const float2 e1 = __half22float2(*(const __half2*)&p1);
            f0 += W[c] * (ux * e0.x + tx * e1.x);
            f1 += W[c] * (ux * e0.y + tx * e1.y);
        }
    }
    return make_float2(f0, f1);
}

// Setup 1: pack levels 1..3 tables to fp16 (half2 per entry) into ws.
__global__ __launch_bounds__(256) void convert_fp16(
    const float* __restrict__ tables, uint32_t* __restrict__ t16)
{
    const int i = blockIdx.x * blockDim.x + threadIdx.x;
    if (i >= 3 * (int)HASHMAP_SIZE) return;
    const float2 e = ((const float2*)tables)[HASHMAP_SIZE + i];  // levels 1..3 contiguous
    const __half2 p = __floats2half2_rn(e.x, e.y);
    t16[i] = *(const uint32_t*)&p;
}

// Setup 2: materialize level-0 dense vertex grid as half2.
__global__ __launch_bounds__(256) void build_dense0(
    const float* __restrict__ tables, uint32_t* __restrict__ dense0)
{
    const int v = blockIdx.x * blockDim.x + threadIdx.x;
    if (v >= DENSE0_N) return;
    const int vx = v / (R0 * R0);
    const int rem = v - vx * (R0 * R0);
    const int vy = rem / R0;
    const int vz = rem - vy * R0;
    const uint32_t h = hash3((uint32_t)vx, (uint32_t)vy, (uint32_t)vz);
    const float2 e = ((const float2*)tables)[h];   // level-0 table at offset 0
    const __half2 p = __floats2half2_rn(e.x, e.y);
    dense0[v] = *(const uint32_t*)&p;
}

// Gather pass for levels 1,2: one fp16 table (2 MB, L2-resident) per launch.
// 256-thread blocks -> high occupancy keeps the per-CU miss slots full.
__global__ __launch_bounds__(256) void pass16_kernel(
    const float* __restrict__ x, const uint32_t* __restrict__ t16,
    float* __restrict__ ws, float r, int n)
{
    const int i = blockIdx.x * blockDim.x + threadIdx.x;
    if (i >= n) return;
    const float px = __builtin_nontemporal_load(x + 3 * (size_t)i + 0);
    const float py = __builtin_nontemporal_load(x + 3 * (size_t)i + 1);
    const float pz = __builtin_nontemporal_load(x + 3 * (size_t)i + 2);
    const float2 e = level_embed_h16(px, py, pz, t16, r);
    v2f v = {e.x, e.y};
    __builtin_nontemporal_store(v, (v2f*)ws + i);
}

extern __shared__ uint32_t s_dense[];   // DENSE0_N packed half2

// Final: level 3 (fp16 gather) + level 0 (LDS dense grid) + combine ws1/ws2.
// 1024 threads (16 waves/CU at 1 block/CU) is enough in-flight gathers to
// fill the per-CU miss slots (~16 waves x 6 lines > 64).
__global__ __launch_bounds__(1024) void final16_kernel(
    const float* __restrict__ x, const uint32_t* __restrict__ t16_l3,
    const uint32_t* __restrict__ dense0,
    const float* __restrict__ ws1, const float* __restrict__ ws2,
    float* __restrict__ out, int n)
{
    for (int i = threadIdx.x; i < DENSE0_N; i += 1024)
        s_dense[i] = dense0[i];
    __syncthreads();

    const size_t stride = (size_t)gridDim.x * 1024;
    for (size_t i = (size_t)blockIdx.x * 1024 + threadIdx.x; i < (size_t)n; i += stride) {
        const float px = __builtin_nontemporal_load(x + 3 * i + 0);
        const float py = __builtin_nontemporal_load(x + 3 * i + 1);
        const float pz = __builtin_nontemporal_load(x + 3 * i + 2);

        // level 3: global fp16 gathers (long latency; issue first)
        const float2 e3 = level_embed_h16(px, py, pz, t16_l3, 512.0f);

        // level 0 from LDS dense grid
        const float sx = px * 30.0f, sy = py * 30.0f, sz = pz * 30.0f;
        const float bx = floorf(sx), by = floorf(sy), bz = floorf(sz);
        const float tx = sx - bx, ty = sy - by, tz = sz - bz;
        const float uxv = 1.0f - tx, uyv = 1.0f - ty, uzv = 1.0f - tz;
        const int ix = (int)bx, iy = (int)by, iz = (int)bz;
        const int lin = (ix * R0 + iy) * R0 + iz;

        float f0 = 0.0f, f1 = 0.0f;
        #pragma unroll
        for (int dx = 0; dx < 2; ++dx) {
            const float wx = dx ? tx : uxv;
            #pragma unroll
            for (int dy = 0; dy < 2; ++dy) {
                const float wxy = wx * (dy ? ty : uyv);
                const int base = lin + (dx * R0 + dy) * R0;   // z-corners adjacent
                const uint32_t p0 = s_dense[base];
                const uint32_t p1 = s_dense[base + 1];
                const float2 c0 = __half22float2(*(const __half2*)&p0);
                const float2 c1 = __half22float2(*(const __half2*)&p1);
                f0 += wxy * (uzv * c0.x + tz * c1.x);
                f1 += wxy * (uzv * c0.y + tz * c1.y);
            }
        }

        const v2f e1 = __builtin_nontemporal_load((const v2f*)ws1 + i);
        const v2f e2 = __builtin_nontemporal_load((const v2f*)ws2 + i);

        v4f* op = (v4f*)(out + 8 * i);
        v4f lo = {f0, f1, e1.x, e1.y};
        v4f hi = {e2.x, e2.y, e3.x, e3.y};
        __builtin_nontemporal_store(lo, op);
        __builtin_nontemporal_store(hi, op + 1);
    }
}

// Fallback (ws too small / attribute failure): fp32 per-level pass into out.
__global__ __launch_bounds__(256) void pass_direct_kernel(
    const float* __restrict__ x, const float* __restrict__ tables,
    float* __restrict__ out, int li, float r, int n)
{
    const int i = blockIdx.x * blockDim.x + threadIdx.x;
    if (i >= n) return;
    const float px = x[3 * (size_t)i + 0];
    const float py = x[3 * (size_t)i + 1];
    const float pz = x[3 * (size_t)i + 2];
    const float2 e = level_embed_p(px, py, pz, tables, li, r);
    float2* op = (float2*)(out + 8 * (size_t)i + 2 * li);
    *op = e;
}

extern "C" void kernel_launch(void* const* d_in, const int* in_sizes, int n_in,
                              void* d_out, int out_size, void* d_ws, size_t ws_size,
                              hipStream_t stream) {
    const float* x = (const float*)d_in[0];        // [N, 3]
    const float* tables = (const float*)d_in[1];   // [4, 2^19, 2]
    float* out = (float*)d_out;                    // [N, 8]
    const int n = in_sizes[0] / 3;

    // ws layout (bytes):
    //   [0, 6 MB)              : fp16 tables for levels 1,2,3 (2 MB each)
    //   [6 MB, 6 MB + 8n)      : ws1 (float2[n])
    //   [.., + 8n)             : ws2 (float2[n])
    //   [.., + DENSE0_BYTES)   : dense0
    const size_t tab16_bytes = 3 * (size_t)HASHMAP_SIZE * 4;
    const size_t ws_needed = tab16_bytes + 2 * (size_t)n * 8 + DENSE0_BYTES;

    bool fused_ok = (ws_size >= ws_needed);
    if (fused_ok) {
        static int attr_ok = -1;
        if (attr_ok < 0) {
            attr_ok = (hipFuncSetAttribute(
                           reinterpret_cast<const void*>(final16_kernel),
                           hipFuncAttributeMaxDynamicSharedMemorySize,
                           DENSE0_BYTES) == hipSuccess) ? 1 : 0;
        }
        fused_ok = (attr_ok == 1);
    }

    if (fused_ok) {
        char* wsb = (char*)d_ws;
        uint32_t* t16   = (uint32_t*)wsb;                       // levels 1..3
        float*    ws1   = (float*)(wsb + tab16_bytes);
        float*    ws2   = (float*)(wsb + tab16_bytes + (size_t)n * 8);
        uint32_t* dense0 = (uint32_t*)(wsb + tab16_bytes + 2 * (size_t)n * 8);

        convert_fp16<<<(3 * HASHMAP_SIZE + 255) / 256, 256, 0, stream>>>(tables, t16);
        build_dense0<<<(DENSE0_N + 255) / 256, 256, 0, stream>>>(tables, dense0);

        const int block = 256;
        const int grid = (n + block - 1) / block;
        pass16_kernel<<<grid, block, 0, stream>>>(x, t16, ws1, 80.0f, n);
        pass16_kernel<<<grid, block, 0, stream>>>(x, t16 + HASHMAP_SIZE, ws2, 210.0f, n);
        // 256 blocks = 1 per CU; uniform work, one LDS stage per CU.
        final16_kernel<<<256, 1024, DENSE0_BYTES, stream>>>(
            x, t16 + 2 * HASHMAP_SIZE, dense0, ws1, ws2, out, n);
    } else {
        const float res[N_LEVELS] = {30.0f, 80.0f, 210.0f, 512.0f};
        const int block = 256;
        const int grid = (n + block - 1) / block;
        for (int li = 0; li < N_LEVELS; ++li) {
            pass_direct_kernel<<<grid, block, 0, stream>>>(
                x, tables, out, li, res[li], n);
        }
    }
}